// Round 6
// baseline (36.850 us; speedup 1.0000x reference)
//
#include <hip/hip_runtime.h>

#define N2 128
#define BLOCK 256        // 4 waves; wave w covers j in [32w, 32w+32)
#define APB 64           // anchors per block (one per lane)
#define BAND 9.5367431640625e-07f   // 2^-20 relative guard band

__device__ __forceinline__ float rdlane(float v, int k) {
    return __int_as_float(__builtin_amdgcn_readlane(__float_as_int(v), k));
}

__global__ __launch_bounds__(BLOCK, 8) void matcher_kernel(
    const float4* __restrict__ boxes1,
    const float4* __restrict__ boxes2,
    float* __restrict__ out_vals,
    float* __restrict__ out_idx,
    float* __restrict__ out_labels,
    int n1)
{
#pragma clang fp contract(off)
    __shared__ float4 s_b2[N2];
    __shared__ float  s_area2[N2];
    __shared__ float  s_q[4][APB];
    __shared__ int    s_ix[4][APB];

    const int t = threadIdx.x;
    if (t < N2) {
        const float4 b = boxes2[t];            // (y1, x1, y2, x2)
        s_b2[t] = b;
        s_area2[t] = (b.z - b.x) * (b.w - b.y);
    }

    const int w    = __builtin_amdgcn_readfirstlane(t >> 6); // wave id, uniform
    const int lane = t & 63;
    const int i    = blockIdx.x * APB + lane;

    const float4 a = boxes1[(i < n1) ? i : 0];
    const float area1 = (a.z - a.x) * (a.w - a.y);

    // lane-distributed register copy of this wave's 32-box window:
    // lane l holds box2[j0 + (l&31)] and its area. No LDS/SMEM in main loop.
    const int j0 = w * 32;
    const float4 bw = boxes2[j0 + (lane & 31)];
    const float  aw = (bw.z - bw.x) * (bw.w - bw.y);

    float bq = -1.0f;          // approx best quotient; first candidate wins
    int   bidx = j0;
    bool  slow = false;

#pragma unroll
    for (int k = 0; k < 32; ++k) {             // k is compile-time constant
        const float by1 = rdlane(bw.x, k);     // v_readlane: VALU pipe only
        const float bx1 = rdlane(bw.y, k);
        const float by2 = rdlane(bw.z, k);
        const float bx2 = rdlane(bw.w, k);
        const float a2  = rdlane(aw,   k);
        const float hy = fmaxf(fminf(a.z, by2) - fmaxf(a.x, by1), 0.0f);
        const float hx = fmaxf(fminf(a.w, bx2) - fmaxf(a.y, bx1), 0.0f);
        const float inter = hy * hx;
        const float um = fmaxf((area1 + a2) - inter, 1e-10f);
        const float q   = inter * __builtin_amdgcn_rcpf(um);
        const float d   = q - bq;
        const float th  = bq * BAND;
        slow = slow | ((inter > 0.0f) & (fabsf(d) <= th));
        if (d > th) { bq = q; bidx = j0 + k; }
    }

    __syncthreads();   // staging visible (placed late: cold paths below use it)

#define FRAC(J, INTER, UM)                                            \
    {                                                                 \
        const float4 b = s_b2[(J)];                                   \
        const float hy = fmaxf(fminf(a.z, b.z) - fmaxf(a.x, b.x), 0.0f); \
        const float hx = fmaxf(fminf(a.w, b.w) - fmaxf(a.y, b.y), 0.0f); \
        INTER = hy * hx;                                              \
        UM = fmaxf((area1 + s_area2[(J)]) - INTER, 1e-10f);           \
    }

    if (slow) {
        // rare: replay this wave's window with exact reference semantics
        float best = -1.0f;
        int   bx = j0;
        for (int k = 0; k < 32; ++k) {
            const int j = j0 + k;
            float inter, um;
            FRAC(j, inter, um)
            const float qq = inter / um;       // exact IEEE divide
            if (qq > best) { best = qq; bx = j; }
        }
        bidx = bx;
    }

    // one exact IEEE divide on the winner reproduces matched_val bitwise
    float qe;
    {
        float inter, um;
        FRAC(bidx, inter, um)                  // per-lane LDS gather, once
        qe = inter / um;
    }

    s_q[w][lane]  = qe;
    s_ix[w][lane] = bidx;
    __syncthreads();

    // merge the 4 wave-partials; ascending wave + strict > == first-max
    if (t < APB) {
        const int ii = blockIdx.x * APB + t;
        if (ii < n1) {
            float q  = s_q[0][t];
            int   ix = s_ix[0][t];
#pragma unroll
            for (int w2 = 1; w2 < 4; ++w2) {
                const float q2 = s_q[w2][t];
                if (q2 > q) { q = q2; ix = s_ix[w2][t]; }
            }
            out_vals[ii]   = q;
            out_idx[ii]    = (float)ix;
            out_labels[ii] = (q >= 0.7f) ? 1.0f : ((q < 0.3f) ? 0.0f : -1.0f);
        }
    }
}

extern "C" void kernel_launch(void* const* d_in, const int* in_sizes, int n_in,
                              void* d_out, int out_size, void* d_ws, size_t ws_size,
                              hipStream_t stream) {
    const float4* boxes1 = (const float4*)d_in[0];
    const float4* boxes2 = (const float4*)d_in[1];
    const int n1 = in_sizes[0] / 4;

    float* out = (float*)d_out;
    float* out_vals   = out;
    float* out_idx    = out + n1;
    float* out_labels = out + 2 * n1;

    const int grid = (n1 + APB - 1) / APB;
    matcher_kernel<<<grid, BLOCK, 0, stream>>>(boxes1, boxes2,
                                               out_vals, out_idx, out_labels, n1);
}

// Round 7
// 32.811 us; speedup vs baseline: 1.1231x; 1.1231x over previous
//
#include <hip/hip_runtime.h>

#define N2 128
#define BLOCK 256        // 4 waves; wave w covers j in [32w, 32w+32)
#define APB 64           // anchors per block (one per lane)
#define BAND 9.5367431640625e-07f   // 2^-20 relative guard band

__global__ void prep_areas(const float4* __restrict__ boxes2,
                           float* __restrict__ areas) {
#pragma clang fp contract(off)
    const int t = threadIdx.x;
    if (t < N2) {
        const float4 b = boxes2[t];
        areas[t] = (b.z - b.x) * (b.w - b.y);   // same expr as reference
    }
}

__global__ __launch_bounds__(BLOCK, 8) void matcher_kernel(
    const float4* __restrict__ boxes1,
    const float4* __restrict__ boxes2,
    const float* __restrict__ areasg,
    float* __restrict__ out_vals,
    float* __restrict__ out_idx,
    float* __restrict__ out_labels,
    int n1)
{
#pragma clang fp contract(off)
    __shared__ float4 s_b2[N2];
    __shared__ float  s_area2[N2];
    __shared__ float  s_q[4][APB];
    __shared__ int    s_ix[4][APB];

    const int t    = threadIdx.x;
    const int w    = __builtin_amdgcn_readfirstlane(t >> 6); // wave id, uniform
    const int lane = t & 63;
    const int i    = blockIdx.x * APB + lane;

    const float4 a = boxes1[(i < n1) ? i : 0];
    const float area1 = (a.z - a.x) * (a.w - a.y);

    const int j0 = w * 32;
    float bq = -1.0f;          // approx best quotient; first candidate wins
    int   bidx = j0;
    bool  slow = false;

    // hot loop: operands via wave-uniform s_load ONLY (boxes2[j], areasg[j]).
    // No LDS, no readlane -> no lgkmcnt cross-pipe drains, no SGPR hazards.
#pragma unroll 8
    for (int k = 0; k < 32; ++k) {
        const int j = j0 + k;                  // wave-uniform
        const float4 b = boxes2[j];            // s_load_dwordx4
        const float a2 = areasg[j];            // s_load_dword
        const float hy = fmaxf(fminf(a.z, b.z) - fmaxf(a.x, b.x), 0.0f);
        const float hx = fmaxf(fminf(a.w, b.w) - fmaxf(a.y, b.y), 0.0f);
        const float inter = hy * hx;
        const float um = fmaxf((area1 + a2) - inter, 1e-10f);
        const float q   = inter * __builtin_amdgcn_rcpf(um);
        const float d   = q - bq;
        const float th  = bq * BAND;
        slow = slow | ((inter > 0.0f) & (fabsf(d) <= th));
        if (d > th) { bq = q; bidx = j0 + k; }
    }

    // cold staging for slow path / final gather / merge — after the loop
    if (t < N2) {
        const float4 b = boxes2[t];
        s_b2[t] = b;
        s_area2[t] = (b.z - b.x) * (b.w - b.y);
    }
    __syncthreads();

#define FRAC(J, INTER, UM)                                            \
    {                                                                 \
        const float4 b = s_b2[(J)];                                   \
        const float hy = fmaxf(fminf(a.z, b.z) - fmaxf(a.x, b.x), 0.0f); \
        const float hx = fmaxf(fminf(a.w, b.w) - fmaxf(a.y, b.y), 0.0f); \
        INTER = hy * hx;                                              \
        UM = fmaxf((area1 + s_area2[(J)]) - INTER, 1e-10f);           \
    }

    if (slow) {
        // rare: replay this wave's window with exact reference semantics
        float best = -1.0f;
        int   bx = j0;
        for (int k = 0; k < 32; ++k) {
            const int j = j0 + k;
            float inter, um;
            FRAC(j, inter, um)
            const float qq = inter / um;       // exact IEEE divide
            if (qq > best) { best = qq; bx = j; }
        }
        bidx = bx;
    }

    // one exact IEEE divide on the winner reproduces matched_val bitwise
    float qe;
    {
        float inter, um;
        FRAC(bidx, inter, um)                  // per-lane LDS gather, once
        qe = inter / um;
    }

    s_q[w][lane]  = qe;
    s_ix[w][lane] = bidx;
    __syncthreads();

    // merge the 4 wave-partials; ascending wave + strict > == first-max
    if (t < APB) {
        const int ii = blockIdx.x * APB + t;
        if (ii < n1) {
            float q  = s_q[0][t];
            int   ix = s_ix[0][t];
#pragma unroll
            for (int w2 = 1; w2 < 4; ++w2) {
                const float q2 = s_q[w2][t];
                if (q2 > q) { q = q2; ix = s_ix[w2][t]; }
            }
            out_vals[ii]   = q;
            out_idx[ii]    = (float)ix;
            out_labels[ii] = (q >= 0.7f) ? 1.0f : ((q < 0.3f) ? 0.0f : -1.0f);
        }
    }
}

extern "C" void kernel_launch(void* const* d_in, const int* in_sizes, int n_in,
                              void* d_out, int out_size, void* d_ws, size_t ws_size,
                              hipStream_t stream) {
    const float4* boxes1 = (const float4*)d_in[0];
    const float4* boxes2 = (const float4*)d_in[1];
    const int n1 = in_sizes[0] / 4;

    float* areas = (float*)d_ws;               // 128 floats scratch

    float* out = (float*)d_out;
    float* out_vals   = out;
    float* out_idx    = out + n1;
    float* out_labels = out + 2 * n1;

    prep_areas<<<1, N2, 0, stream>>>(boxes2, areas);

    const int grid = (n1 + APB - 1) / APB;
    matcher_kernel<<<grid, BLOCK, 0, stream>>>(boxes1, boxes2, areas,
                                               out_vals, out_idx, out_labels, n1);
}